// Round 2
// baseline (9543.919 us; speedup 1.0000x reference)
//
#include <hip/hip_runtime.h>

// LSTM: B=512, T=512, D=128, H=256, L=2, O=1
// Persistent-kernel design:
//   grid 256 = 16 row-groups (32 rows each) x 16 col-splits (16 h-cols each).
//   Block (m,n) owns rows [32m,32m+32) and h-cols [16n,16n+16) of BOTH layers.
//   Weights (the block's 64 gate-columns of wi0/hi0/wi1/hi1) are held in
//   registers as bf16 MFMA B-fragments. c-state in LDS. h-state exchanged
//   via d_ws (bf16, parity double-buffered). L1 runs one step behind L0 so
//   one 16-block group barrier per iteration suffices (513 barriers).

#define G4 1024

typedef __bf16 bf16x8 __attribute__((ext_vector_type(8)));
typedef float f32x4 __attribute__((ext_vector_type(4)));
typedef unsigned short u16x8 __attribute__((ext_vector_type(8)));
typedef unsigned short u16x4 __attribute__((ext_vector_type(4)));

#define MFMA(a, b, c) __builtin_amdgcn_mfma_f32_16x16x32_bf16(a, b, c, 0, 0, 0)

__device__ __forceinline__ unsigned short f2bf(float f) {
  unsigned u = __builtin_bit_cast(unsigned, f);
  u += 0x7fffu + ((u >> 16) & 1u);   // RNE
  return (unsigned short)(u >> 16);
}
__device__ __forceinline__ float bf2f(unsigned v) {
  v <<= 16;
  return __builtin_bit_cast(float, v);
}
__device__ __forceinline__ float sigm(float x) { return 1.f / (1.f + __expf(-x)); }
__device__ __forceinline__ float tanh_(float x) {
  float e = __expf(-2.f * fabsf(x));
  float t = (1.f - e) / (1.f + e);
  return (x < 0.f) ? -t : t;
}

extern "C" __global__ void __launch_bounds__(256, 1)
lstm_persist(const float* __restrict__ x, const float* __restrict__ h0in,
             const float* __restrict__ c0in, const float* __restrict__ wi0,
             const float* __restrict__ hi0, const float* __restrict__ b0,
             const float* __restrict__ wi1, const float* __restrict__ hi1,
             const float* __restrict__ b1, const float* __restrict__ fcw,
             const float* __restrict__ fcb, float* __restrict__ out,
             unsigned* ws_u32) {
  const int bid = blockIdx.x;
  const int m = bid >> 4, n = bid & 15;
  const int row0 = m * 32;
  const int hc0 = n * 16;
  const int tid = threadIdx.x;
  const int w = tid >> 6;            // wave = gate type (i,f,g,o)
  const int lane = tid & 63;
  const int lc = lane & 15;          // col within 16
  const int kl = (lane >> 4) * 8;    // k offset within a K=32 step
  const int arow = lane & 15;        // A-fragment row

  // d_ws layout (u32 units): h0 buf [2][512][128], h1 buf [2][512][128],
  // then 16 barrier counters at 128B stride (byte offset 1 MiB).
  unsigned* h0b = ws_u32;
  unsigned* h1b = ws_u32 + 2 * 65536;
  unsigned* ctr = ws_u32 + 4 * 65536 + m * 32;

  __shared__ unsigned short x_lds[32][136];    // x_t tile, bf16, pad->136
  __shared__ unsigned short h0_lds[32][264];   // h0[i-1] slab (full 256 cols)
  __shared__ unsigned short h1_lds[32][264];   // h1[i-2] slab
  __shared__ float gates0[32][68];
  __shared__ float gates1[32][68];
  __shared__ float c_st[2][32][16];
  __shared__ float bias_s[2][64];

  // ---- load weight B-fragments into registers (persistent) ----
  // B-frag for MFMA 16x16x32: lane holds W[k = kstep*32 + (lane>>4)*8 + j][col0 + (lane&15)]
  bf16x8 bw0[12];  // [0..3] wi0 (K=128), [4..11] hi0 (K=256)
  bf16x8 bw1[16];  // [0..7] wi1 (A=h0), [8..15] hi1 (A=h1)
  const int gcol = w * 256 + hc0 + lc;  // global gate column
  {
#pragma unroll
    for (int ks = 0; ks < 4; ++ks) {
      u16x8 v;
#pragma unroll
      for (int j = 0; j < 8; ++j) v[j] = f2bf(wi0[(ks * 32 + kl + j) * G4 + gcol]);
      bw0[ks] = __builtin_bit_cast(bf16x8, v);
    }
#pragma unroll
    for (int ks = 0; ks < 8; ++ks) {
      u16x8 v;
#pragma unroll
      for (int j = 0; j < 8; ++j) v[j] = f2bf(hi0[(ks * 32 + kl + j) * G4 + gcol]);
      bw0[4 + ks] = __builtin_bit_cast(bf16x8, v);
    }
#pragma unroll
    for (int ks = 0; ks < 8; ++ks) {
      u16x8 v;
#pragma unroll
      for (int j = 0; j < 8; ++j) v[j] = f2bf(wi1[(ks * 32 + kl + j) * G4 + gcol]);
      bw1[ks] = __builtin_bit_cast(bf16x8, v);
    }
#pragma unroll
    for (int ks = 0; ks < 8; ++ks) {
      u16x8 v;
#pragma unroll
      for (int j = 0; j < 8; ++j) v[j] = f2bf(hi1[(ks * 32 + kl + j) * G4 + gcol]);
      bw1[8 + ks] = __builtin_bit_cast(bf16x8, v);
    }
  }

  if (tid < 64) {
    bias_s[0][tid] = b0[(tid >> 4) * 256 + hc0 + (tid & 15)];
  } else if (tid < 128) {
    int t2 = tid - 64;
    bias_s[1][t2] = b1[(t2 >> 4) * 256 + hc0 + (t2 & 15)];
  }

  // ---- init c-state (LDS) and h-state (global, parity 1 = "step -1") ----
  const int ac = tid & 15, ar = tid >> 4;  // activation map: col, row(0..15)
#pragma unroll
  for (int half = 0; half < 2; ++half) {
    int r = ar + half * 16;
    int rg = row0 + r;
    c_st[0][r][ac] = c0in[rg * 256 + hc0 + ac];
    c_st[1][r][ac] = c0in[131072 + rg * 256 + hc0 + ac];
    unsigned short hb0 = f2bf(h0in[rg * 256 + hc0 + ac]);
    unsigned short hb1 = f2bf(h0in[131072 + rg * 256 + hc0 + ac]);
    unsigned o0 = (unsigned)__shfl_down((int)hb0, 1) & 0xffffu;
    unsigned o1 = (unsigned)__shfl_down((int)hb1, 1) & 0xffffu;
    if (!(ac & 1)) {
      int ui = 65536 + rg * 128 + ((hc0 + ac) >> 1);
      h0b[ui] = (unsigned)hb0 | (o0 << 16);
      h1b[ui] = (unsigned)hb1 | (o1 << 16);
    }
  }

  // ---- group barrier (16 blocks of row-group m), agent-scope ----
  unsigned bar = 0;
  auto barrier = [&]() {
    ++bar;
    __syncthreads();
    if (tid == 0) {
      __threadfence();               // release: flush h writes to MALL
      atomicAdd(ctr, 1u);
      unsigned tgt = 16u * bar;
      int sp = 0;
      while (__hip_atomic_load(ctr, __ATOMIC_RELAXED, __HIP_MEMORY_SCOPE_AGENT) < tgt &&
             ++sp < (1 << 18))
        __builtin_amdgcn_s_sleep(2);
      __threadfence();               // acquire: invalidate stale lines
    }
    __syncthreads();
  };
  barrier();  // init writes visible

  const int sr = tid >> 3, seg = tid & 7;  // staging map: row, 8-way segment

  // iteration i: layer0 computes step i (i<512); layer1 computes step i-1 (i>0)
  for (int i = 0; i < 513; ++i) {
    // ---- stage x_t, h0[i-1], h1[i-2] into LDS ----
    if (i < 512) {
      const float4* xrow = (const float4*)(x + (size_t)(row0 + sr) * (512 * 128) + (size_t)i * 128);
#pragma unroll
      for (int q = 0; q < 4; ++q) {
        float4 v = xrow[seg + q * 8];
        u16x4 p;
        p[0] = f2bf(v.x); p[1] = f2bf(v.y); p[2] = f2bf(v.z); p[3] = f2bf(v.w);
        *(u16x4*)&x_lds[sr][(seg + q * 8) * 4] = p;
      }
    }
    {
      const unsigned* hrow = h0b + ((i + 1) & 1) * 65536 + (row0 + sr) * 128;
#pragma unroll
      for (int q = 0; q < 16; ++q)
        *(unsigned*)&h0_lds[sr][(seg + q * 8) * 2] = hrow[seg + q * 8];
    }
    if (i > 0) {
      const unsigned* hrow = h1b + (i & 1) * 65536 + (row0 + sr) * 128;
#pragma unroll
      for (int q = 0; q < 16; ++q)
        *(unsigned*)&h1_lds[sr][(seg + q * 8) * 2] = hrow[seg + q * 8];
    }
    __syncthreads();

    // ---- MFMAs: wave w computes gate-type w, rows 0..31 (2 M-tiles), 16 cols ----
    f32x4 a00{0.f, 0.f, 0.f, 0.f}, a01{0.f, 0.f, 0.f, 0.f};
    f32x4 a10{0.f, 0.f, 0.f, 0.f}, a11{0.f, 0.f, 0.f, 0.f};
    if (i < 512) {
#pragma unroll
      for (int ks = 0; ks < 4; ++ks) {
        bf16x8 a0 = *(const bf16x8*)&x_lds[arow][ks * 32 + kl];
        bf16x8 a1 = *(const bf16x8*)&x_lds[16 + arow][ks * 32 + kl];
        a00 = MFMA(a0, bw0[ks], a00);
        a01 = MFMA(a1, bw0[ks], a01);
      }
    }
#pragma unroll
    for (int ks = 0; ks < 8; ++ks) {   // h0 slab feeds L0 (hi0) and L1 (wi1)
      bf16x8 a0 = *(const bf16x8*)&h0_lds[arow][ks * 32 + kl];
      bf16x8 a1 = *(const bf16x8*)&h0_lds[16 + arow][ks * 32 + kl];
      if (i < 512) {
        a00 = MFMA(a0, bw0[4 + ks], a00);
        a01 = MFMA(a1, bw0[4 + ks], a01);
      }
      if (i > 0) {
        a10 = MFMA(a0, bw1[ks], a10);
        a11 = MFMA(a1, bw1[ks], a11);
      }
    }
    if (i > 0) {
#pragma unroll
      for (int ks = 0; ks < 8; ++ks) {
        bf16x8 a0 = *(const bf16x8*)&h1_lds[arow][ks * 32 + kl];
        bf16x8 a1 = *(const bf16x8*)&h1_lds[16 + arow][ks * 32 + kl];
        a10 = MFMA(a0, bw1[8 + ks], a10);
        a11 = MFMA(a1, bw1[8 + ks], a11);
      }
    }
    {
      int col = w * 16 + lc;
      int rbase = (lane >> 4) * 4;  // C/D: row=(lane>>4)*4+j, col=lane&15
      if (i < 512) {
#pragma unroll
        for (int j = 0; j < 4; ++j) {
          gates0[rbase + j][col] = a00[j];
          gates0[16 + rbase + j][col] = a01[j];
        }
      }
      if (i > 0) {
#pragma unroll
        for (int j = 0; j < 4; ++j) {
          gates1[rbase + j][col] = a10[j];
          gates1[16 + rbase + j][col] = a11[j];
        }
      }
    }
    __syncthreads();

    // ---- activations + state update ----
    if (i < 512) {
#pragma unroll
      for (int half = 0; half < 2; ++half) {
        int r = ar + half * 16;
        float gi = gates0[r][ac] + bias_s[0][ac];
        float gf = gates0[r][16 + ac] + bias_s[0][16 + ac];
        float gg = gates0[r][32 + ac] + bias_s[0][32 + ac];
        float go = gates0[r][48 + ac] + bias_s[0][48 + ac];
        float ii = sigm(gi), ff = sigm(gf), g = tanh_(gg), oo = sigm(go);
        float c = ff * c_st[0][r][ac] + ii * g;
        c_st[0][r][ac] = c;
        float h = oo * tanh_(c);
        unsigned short hb = f2bf(h);
        unsigned other = (unsigned)__shfl_down((int)hb, 1) & 0xffffu;
        if (!(ac & 1))
          h0b[(i & 1) * 65536 + (row0 + r) * 128 + ((hc0 + ac) >> 1)] =
              (unsigned)hb | (other << 16);
      }
    }
    if (i > 0) {
#pragma unroll
      for (int half = 0; half < 2; ++half) {
        int r = ar + half * 16;
        float gi = gates1[r][ac] + bias_s[1][ac];
        float gf = gates1[r][16 + ac] + bias_s[1][16 + ac];
        float gg = gates1[r][32 + ac] + bias_s[1][32 + ac];
        float go = gates1[r][48 + ac] + bias_s[1][48 + ac];
        float ii = sigm(gi), ff = sigm(gf), g = tanh_(gg), oo = sigm(go);
        float c = ff * c_st[1][r][ac] + ii * g;
        c_st[1][r][ac] = c;
        float h = oo * tanh_(c);
        unsigned short hb = f2bf(h);
        unsigned other = (unsigned)__shfl_down((int)hb, 1) & 0xffffu;
        if (!(ac & 1))
          h1b[((i - 1) & 1) * 65536 + (row0 + r) * 128 + ((hc0 + ac) >> 1)] =
              (unsigned)hb | (other << 16);
      }
    }
    barrier();
  }

  // ---- epilogue: out[b] = h1_final[b,:] . fc_w + fc_b (final parity = 1) ----
  if (n == 0) {
    int r = tid >> 3, sg = tid & 7;
    const unsigned* hrow = h1b + 65536 + (row0 + r) * 128;
    float sum = 0.f;
#pragma unroll
    for (int q = 0; q < 16; ++q) {
      unsigned v = hrow[sg + q * 8];
      int k = (sg + q * 8) * 2;
      sum += bf2f(v & 0xffffu) * fcw[k];
      sum += bf2f(v >> 16) * fcw[k + 1];
    }
    sum += __shfl_down(sum, 4, 8);
    sum += __shfl_down(sum, 2, 8);
    sum += __shfl_down(sum, 1, 8);
    if (sg == 0) out[row0 + r] = sum + fcb[0];
  }
}

extern "C" void kernel_launch(void* const* d_in, const int* in_sizes, int n_in,
                              void* d_out, int out_size, void* d_ws, size_t ws_size,
                              hipStream_t stream) {
  // zero the 16 barrier counters (byte offset 1 MiB, 2 KiB region)
  hipMemsetAsync((char*)d_ws + 1048576, 0, 2048, stream);
  lstm_persist<<<dim3(256), dim3(256), 0, stream>>>(
      (const float*)d_in[0], (const float*)d_in[1], (const float*)d_in[2],
      (const float*)d_in[3], (const float*)d_in[4], (const float*)d_in[5],
      (const float*)d_in[6], (const float*)d_in[7], (const float*)d_in[8],
      (const float*)d_in[9], (const float*)d_in[10], (float*)d_out,
      (unsigned*)d_ws);
}

// Round 3
// 4833.674 us; speedup vs baseline: 1.9745x; 1.9745x over previous
//
#include <hip/hip_runtime.h>

// LSTM: B=512, T=512, D=128, H=256, L=2, O=1
// Persistent kernel, grid 256 = 16 row-groups (32 rows) x 16 col-splits (16 h-cols).
// Weights in VGPRs (bf16 MFMA B-frags). c-state in LDS. h exchanged via d_ws in
// bf16 with RELAXED AGENT-scope (sc0 sc1, MALL-coherent) accesses — no cache
// fences. Sync: per-wave flag words, release-by-store-ack (s_waitcnt vmcnt(0)).
// L1 runs one step behind L0; split flags let h0 publish early.

#define G4 1024

typedef __bf16 bf16x8 __attribute__((ext_vector_type(8)));
typedef float f32x4 __attribute__((ext_vector_type(4)));
typedef unsigned short u16x8 __attribute__((ext_vector_type(8)));

#define MFMA(a, b, c) __builtin_amdgcn_mfma_f32_16x16x32_bf16(a, b, c, 0, 0, 0)
#define AGENT __HIP_MEMORY_SCOPE_AGENT
// gates bank swizzle: flip bit4 of col with bit2 of row (writes 4->2-way, reads stay 2-way)
#define GIDX(r, c) ((c) ^ ((((r) >> 2) & 1) << 4))

__device__ __forceinline__ unsigned short f2bf(float f) {
  unsigned u = __builtin_bit_cast(unsigned, f);
  u += 0x7fffu + ((u >> 16) & 1u);  // RNE
  return (unsigned short)(u >> 16);
}
__device__ __forceinline__ float bf2f(unsigned v) {
  v <<= 16;
  return __builtin_bit_cast(float, v);
}
__device__ __forceinline__ float sigm(float x) { return 1.f / (1.f + __expf(-x)); }
__device__ __forceinline__ float tanh_(float x) {
  float e = __expf(-2.f * fabsf(x));
  float t = (1.f - e) / (1.f + e);
  return (x < 0.f) ? -t : t;
}

extern "C" __global__ void __launch_bounds__(256, 1)
lstm_persist(const float* __restrict__ x, const float* __restrict__ h0in,
             const float* __restrict__ c0in, const float* __restrict__ wi0,
             const float* __restrict__ hi0, const float* __restrict__ b0,
             const float* __restrict__ wi1, const float* __restrict__ hi1,
             const float* __restrict__ b1, const float* __restrict__ fcw,
             const float* __restrict__ fcb, float* __restrict__ out,
             unsigned* ws_u32) {
  const int bid = blockIdx.x;
  const int m = bid >> 4, n = bid & 15;
  const int row0 = m * 32;
  const int hc0 = n * 16;
  const int tid = threadIdx.x;
  const int w = tid >> 6;            // wave index (= gate type for MFMA phase)
  const int lane = tid & 63;
  const int lc = lane & 15;
  const int kl = (lane >> 4) * 8;
  const int arow = lane & 15;

  // ws (u32): h0 [2][512][128], h1 [2][512][128], flags at 1 MiB:
  //   flg0[256 blocks][4 waves], flg1[256][4]
  unsigned* h0b = ws_u32;
  unsigned* h1b = ws_u32 + 131072;
  unsigned* flg0 = ws_u32 + 262144;
  unsigned* flg1 = flg0 + 1024;

  __shared__ unsigned short x_lds[32][136];   // row stride 272B (u32-writable)
  __shared__ unsigned short h0_lds[32][264];  // row stride 528B
  __shared__ unsigned short h1_lds[32][264];
  __shared__ float gates0[32][72];
  __shared__ float gates1[32][72];
  __shared__ float c_st[2][32][16];
  __shared__ float bias_s[2][64];

  // ---- persistent weight B-fragments: lane holds W[k=ks*32+kl+j][gcol] ----
  bf16x8 bw0[12];  // [0..3] wi0 (K=128), [4..11] hi0 (K=256)
  bf16x8 bw1[16];  // [0..7] wi1, [8..15] hi1
  const int gcol = w * 256 + hc0 + lc;
  {
#pragma unroll
    for (int ks = 0; ks < 4; ++ks) {
      u16x8 v;
#pragma unroll
      for (int j = 0; j < 8; ++j) v[j] = f2bf(wi0[(ks * 32 + kl + j) * G4 + gcol]);
      bw0[ks] = __builtin_bit_cast(bf16x8, v);
    }
#pragma unroll
    for (int ks = 0; ks < 8; ++ks) {
      u16x8 v;
#pragma unroll
      for (int j = 0; j < 8; ++j) v[j] = f2bf(hi0[(ks * 32 + kl + j) * G4 + gcol]);
      bw0[4 + ks] = __builtin_bit_cast(bf16x8, v);
    }
#pragma unroll
    for (int ks = 0; ks < 8; ++ks) {
      u16x8 v;
#pragma unroll
      for (int j = 0; j < 8; ++j) v[j] = f2bf(wi1[(ks * 32 + kl + j) * G4 + gcol]);
      bw1[ks] = __builtin_bit_cast(bf16x8, v);
    }
#pragma unroll
    for (int ks = 0; ks < 8; ++ks) {
      u16x8 v;
#pragma unroll
      for (int j = 0; j < 8; ++j) v[j] = f2bf(hi1[(ks * 32 + kl + j) * G4 + gcol]);
      bw1[8 + ks] = __builtin_bit_cast(bf16x8, v);
    }
  }

  if (tid < 64) {
    bias_s[0][tid] = b0[(tid >> 4) * 256 + hc0 + (tid & 15)];
  } else if (tid < 128) {
    int t2 = tid - 64;
    bias_s[1][t2] = b1[(t2 >> 4) * 256 + hc0 + (t2 & 15)];
  }

  // ---- init: c in LDS; h seeds to parity-1 slabs (agent-coherent stores) ----
  const int ac = tid & 15, ar = tid >> 4;
#pragma unroll
  for (int half = 0; half < 2; ++half) {
    int r = ar + half * 16;
    int rg = row0 + r;
    c_st[0][r][ac] = c0in[rg * 256 + hc0 + ac];
    c_st[1][r][ac] = c0in[131072 + rg * 256 + hc0 + ac];
    unsigned short hb0 = f2bf(h0in[rg * 256 + hc0 + ac]);
    unsigned short hb1 = f2bf(h0in[131072 + rg * 256 + hc0 + ac]);
    unsigned o0 = (unsigned)__shfl_down((int)hb0, 1) & 0xffffu;
    unsigned o1 = (unsigned)__shfl_down((int)hb1, 1) & 0xffffu;
    if (!(ac & 1)) {
      int ui = 65536 + rg * 128 + ((hc0 + ac) >> 1);
      __hip_atomic_store(h0b + ui, (unsigned)hb0 | (o0 << 16), __ATOMIC_RELAXED, AGENT);
      __hip_atomic_store(h1b + ui, (unsigned)hb1 | (o1 << 16), __ATOMIC_RELAXED, AGENT);
    }
  }
  asm volatile("s_waitcnt vmcnt(0)" ::: "memory");  // wave's seeds acked at MALL
  if (lane == 0) {
    __hip_atomic_store(flg0 + (m * 16 + n) * 4 + w, 1u, __ATOMIC_RELAXED, AGENT);
    __hip_atomic_store(flg1 + (m * 16 + n) * 4 + w, 1u, __ATOMIC_RELAXED, AGENT);
  }

  // ---- x prefetch (registers): wave w stages rows srow..srow+8 ----
  const int srow = 8 * w;
  float2 fr[8];
#pragma unroll
  for (int rr = 0; rr < 8; ++rr)
    fr[rr] = *(const float2*)(x + ((size_t)(row0 + srow + rr) << 16) + 2 * lane);

  // poll all 64 wave-flags of this row-group (lane i watches flag i)
  auto waitflags = [&](unsigned* base, unsigned need) {
    int sp = 0;
    while (__hip_atomic_load(base + lane, __ATOMIC_RELAXED, AGENT) < need &&
           ++sp < (1 << 18)) {}
    __builtin_amdgcn_sched_barrier(0);
    asm volatile("" ::: "memory");
  };

  // iter i: L0 computes step i (i<512); L1 computes step i-1 (i>0).
  // flg0 = k  <=>  h0[k-2] published. flg1 = k  <=>  h1[k-2] published.
  for (int i = 0; i < 513; ++i) {
    waitflags(flg0 + m * 64, (unsigned)(i + 1));
    if (i >= 1) waitflags(flg1 + m * 64, (unsigned)i);

    // ---- stage x[i] from prefetch regs; issue prefetch x[i+1] ----
    if (i < 512) {
#pragma unroll
      for (int rr = 0; rr < 8; ++rr) {
        unsigned p = (unsigned)f2bf(fr[rr].x) | ((unsigned)f2bf(fr[rr].y) << 16);
        ((unsigned*)&x_lds[srow + rr][0])[lane] = p;
      }
      if (i + 1 < 512) {
#pragma unroll
        for (int rr = 0; rr < 8; ++rr)
          fr[rr] = *(const float2*)(x + ((size_t)(row0 + srow + rr) << 16) +
                                    (size_t)(i + 1) * 128 + 2 * lane);
      }
    }
    // ---- stage h0[i-1] (parity (i+1)&1) — lane-contiguous, conflict-free ----
    {
      const unsigned* hp = h0b + ((i + 1) & 1) * 65536 + (row0 + srow) * 128;
#pragma unroll
      for (int rr = 0; rr < 8; ++rr) {
        unsigned v0 = __hip_atomic_load(hp + rr * 128 + lane, __ATOMIC_RELAXED, AGENT);
        unsigned v1 = __hip_atomic_load(hp + rr * 128 + 64 + lane, __ATOMIC_RELAXED, AGENT);
        unsigned* dst = (unsigned*)&h0_lds[srow + rr][0];
        dst[lane] = v0;
        dst[64 + lane] = v1;
      }
    }
    // ---- stage h1[i-2] (parity i&1) ----
    if (i >= 1) {
      const unsigned* hp = h1b + (i & 1) * 65536 + (row0 + srow) * 128;
#pragma unroll
      for (int rr = 0; rr < 8; ++rr) {
        unsigned v0 = __hip_atomic_load(hp + rr * 128 + lane, __ATOMIC_RELAXED, AGENT);
        unsigned v1 = __hip_atomic_load(hp + rr * 128 + 64 + lane, __ATOMIC_RELAXED, AGENT);
        unsigned* dst = (unsigned*)&h1_lds[srow + rr][0];
        dst[lane] = v0;
        dst[64 + lane] = v1;
      }
    }
    __syncthreads();

    // ---- MFMA: wave w = gate type w, rows 0..31, 16 cols ----
    f32x4 a00{0.f, 0.f, 0.f, 0.f}, a01{0.f, 0.f, 0.f, 0.f};
    f32x4 a10{0.f, 0.f, 0.f, 0.f}, a11{0.f, 0.f, 0.f, 0.f};
    if (i < 512) {
#pragma unroll
      for (int ks = 0; ks < 4; ++ks) {
        bf16x8 a0 = *(const bf16x8*)&x_lds[arow][ks * 32 + kl];
        bf16x8 a1 = *(const bf16x8*)&x_lds[16 + arow][ks * 32 + kl];
        a00 = MFMA(a0, bw0[ks], a00);
        a01 = MFMA(a1, bw0[ks], a01);
      }
    }
#pragma unroll
    for (int ks = 0; ks < 8; ++ks) {  // h0 slab feeds L0 (hi0) and L1 (wi1)
      bf16x8 a0 = *(const bf16x8*)&h0_lds[arow][ks * 32 + kl];
      bf16x8 a1 = *(const bf16x8*)&h0_lds[16 + arow][ks * 32 + kl];
      if (i < 512) {
        a00 = MFMA(a0, bw0[4 + ks], a00);
        a01 = MFMA(a1, bw0[4 + ks], a01);
      }
      if (i > 0) {
        a10 = MFMA(a0, bw1[ks], a10);
        a11 = MFMA(a1, bw1[ks], a11);
      }
    }
    if (i > 0) {
#pragma unroll
      for (int ks = 0; ks < 8; ++ks) {
        bf16x8 a0 = *(const bf16x8*)&h1_lds[arow][ks * 32 + kl];
        bf16x8 a1 = *(const bf16x8*)&h1_lds[16 + arow][ks * 32 + kl];
        a10 = MFMA(a0, bw1[8 + ks], a10);
        a11 = MFMA(a1, bw1[8 + ks], a11);
      }
    }
    {
      int col = w * 16 + lc;
      int rbase = (lane >> 4) * 4;  // C/D: row=(lane>>4)*4+j, col=lane&15
      if (i < 512) {
#pragma unroll
        for (int j = 0; j < 4; ++j) {
          gates0[rbase + j][GIDX(rbase + j, col)] = a00[j];
          gates0[16 + rbase + j][GIDX(16 + rbase + j, col)] = a01[j];
        }
      }
      if (i > 0) {
#pragma unroll
        for (int j = 0; j < 4; ++j) {
          gates1[rbase + j][GIDX(rbase + j, col)] = a10[j];
          gates1[16 + rbase + j][GIDX(16 + rbase + j, col)] = a11[j];
        }
      }
    }
    __syncthreads();

    // ---- act0: h0[i] -> parity i&1; publish flag0 early ----
    if (i < 512) {
#pragma unroll
      for (int half = 0; half < 2; ++half) {
        int r = ar + half * 16;
        float gi = gates0[r][GIDX(r, ac)] + bias_s[0][ac];
        float gf = gates0[r][GIDX(r, 16 + ac)] + bias_s[0][16 + ac];
        float gg = gates0[r][GIDX(r, 32 + ac)] + bias_s[0][32 + ac];
        float go = gates0[r][GIDX(r, 48 + ac)] + bias_s[0][48 + ac];
        float ii = sigm(gi), ff = sigm(gf), g = tanh_(gg), oo = sigm(go);
        float c = ff * c_st[0][r][ac] + ii * g;
        c_st[0][r][ac] = c;
        float h = oo * tanh_(c);
        unsigned short hb = f2bf(h);
        unsigned other = (unsigned)__shfl_down((int)hb, 1) & 0xffffu;
        if (!(ac & 1))
          __hip_atomic_store(
              h0b + (i & 1) * 65536 + (row0 + r) * 128 + ((hc0 + ac) >> 1),
              (unsigned)hb | (other << 16), __ATOMIC_RELAXED, AGENT);
      }
      asm volatile("s_waitcnt vmcnt(0)" ::: "memory");  // wave's h0 acked
      if (lane == 0)
        __hip_atomic_store(flg0 + (m * 16 + n) * 4 + w, (unsigned)(i + 2),
                           __ATOMIC_RELAXED, AGENT);
    }
    // ---- act1: h1[i-1] -> parity (i-1)&1; publish flag1 ----
    if (i > 0) {
#pragma unroll
      for (int half = 0; half < 2; ++half) {
        int r = ar + half * 16;
        float gi = gates1[r][GIDX(r, ac)] + bias_s[1][ac];
        float gf = gates1[r][GIDX(r, 16 + ac)] + bias_s[1][16 + ac];
        float gg = gates1[r][GIDX(r, 32 + ac)] + bias_s[1][32 + ac];
        float go = gates1[r][GIDX(r, 48 + ac)] + bias_s[1][48 + ac];
        float ii = sigm(gi), ff = sigm(gf), g = tanh_(gg), oo = sigm(go);
        float c = ff * c_st[1][r][ac] + ii * g;
        c_st[1][r][ac] = c;
        float h = oo * tanh_(c);
        unsigned short hb = f2bf(h);
        unsigned other = (unsigned)__shfl_down((int)hb, 1) & 0xffffu;
        if (!(ac & 1))
          __hip_atomic_store(
              h1b + ((i - 1) & 1) * 65536 + (row0 + r) * 128 + ((hc0 + ac) >> 1),
              (unsigned)hb | (other << 16), __ATOMIC_RELAXED, AGENT);
      }
      asm volatile("s_waitcnt vmcnt(0)" ::: "memory");  // wave's h1 acked
      if (lane == 0)
        __hip_atomic_store(flg1 + (m * 16 + n) * 4 + w, (unsigned)(i + 1),
                           __ATOMIC_RELAXED, AGENT);
    }
  }

  // ---- epilogue: out[b] = h1[511][b,:] . fc_w + fc_b (parity 1) ----
  if (n == 0) {
    waitflags(flg1 + m * 64, 513u);
    int r = tid >> 3, sg = tid & 7;
    const unsigned* hrow = h1b + 65536 + (row0 + r) * 128;
    float sum = 0.f;
#pragma unroll
    for (int q = 0; q < 16; ++q) {
      unsigned v = __hip_atomic_load(hrow + sg + q * 8, __ATOMIC_RELAXED, AGENT);
      int k2 = (sg + q * 8) * 2;
      sum += bf2f(v & 0xffffu) * fcw[k2];
      sum += bf2f(v >> 16) * fcw[k2 + 1];
    }
    sum += __shfl_down(sum, 4, 8);
    sum += __shfl_down(sum, 2, 8);
    sum += __shfl_down(sum, 1, 8);
    if (sg == 0) out[row0 + r] = sum + fcb[0];
  }
}

extern "C" void kernel_launch(void* const* d_in, const int* in_sizes, int n_in,
                              void* d_out, int out_size, void* d_ws, size_t ws_size,
                              hipStream_t stream) {
  // zero the flag region (byte offset 1 MiB, 8 KiB)
  hipMemsetAsync((char*)d_ws + 1048576, 0, 8192, stream);
  lstm_persist<<<dim3(256), dim3(256), 0, stream>>>(
      (const float*)d_in[0], (const float*)d_in[1], (const float*)d_in[2],
      (const float*)d_in[3], (const float*)d_in[4], (const float*)d_in[5],
      (const float*)d_in[6], (const float*)d_in[7], (const float*)d_in[8],
      (const float*)d_in[9], (const float*)d_in[10], (float*)d_out,
      (unsigned*)d_ws);
}

// Round 5
// 2790.588 us; speedup vs baseline: 3.4200x; 1.7321x over previous
//
#include <hip/hip_runtime.h>

// LSTM B=512 T=512 D=128 H=256 L=2 O=1 — persistent kernel, agent-scope exchange
// (r3-proven sc0 sc1 semantics), serialization-trimmed:
//   - 16 row-groups (32 rows) x 16 col-splits (16 h-cols), static mapping.
//   - ONE merged flag-pair poll per iter (dwordx2), ONE merged store-drain +
//     dual-flag post per iter.
//   - L1 lags L0 by TWO steps; wi1*h0 partial is computed one iteration early
//     (off critical path) and carried in VGPRs; x*wi0 runs pre-poll.
//   - Weights in VGPRs (bf16 MFMA B-frags), c-state + biases in registers.

#define G4 1024

typedef __bf16 bf16x8 __attribute__((ext_vector_type(8)));
typedef float f32x4 __attribute__((ext_vector_type(4)));
typedef unsigned short u16x8 __attribute__((ext_vector_type(8)));

#define MFMA(a, b, c) __builtin_amdgcn_mfma_f32_16x16x32_bf16(a, b, c, 0, 0, 0)
// gates bank swizzle: flip col bit4 with row bit2 (stride 72 f32)
#define GIDX(r, c) ((c) ^ ((((r) >> 2) & 1) << 4))

__device__ __forceinline__ unsigned short f2bf(float f) {
  unsigned u = __builtin_bit_cast(unsigned, f);
  u += 0x7fffu + ((u >> 16) & 1u);  // RNE
  return (unsigned short)(u >> 16);
}
__device__ __forceinline__ float bf2f(unsigned v) {
  v <<= 16;
  return __builtin_bit_cast(float, v);
}
__device__ __forceinline__ float sigm(float x) { return 1.f / (1.f + __expf(-x)); }
__device__ __forceinline__ float tanh_(float x) {
  float e = __expf(-2.f * fabsf(x));
  float t = (1.f - e) / (1.f + e);
  return (x < 0.f) ? -t : t;
}

// Agent-coherent (MALL) global ops — r3-proven sc0 sc1 semantics.
template <int IMM>
__device__ __forceinline__ unsigned g_load_i(const unsigned* p) {
  unsigned r;
  asm volatile("global_load_dword %0, %1, off offset:%c2 sc0 sc1"
               : "=v"(r) : "v"(p), "i"(IMM) : "memory");
  return r;
}
__device__ __forceinline__ void g_store1(unsigned* p, unsigned v) {
  asm volatile("global_store_dword %0, %1, off sc0 sc1" ::"v"(p), "v"(v) : "memory");
}
__device__ __forceinline__ unsigned long long g_load2(const unsigned* p) {
  unsigned long long r;
  asm volatile("global_load_dwordx2 %0, %1, off sc0 sc1"
               : "=v"(r) : "v"(p) : "memory");
  return r;
}
__device__ __forceinline__ void g_store2(unsigned* p, unsigned long long v) {
  asm volatile("global_store_dwordx2 %0, %1, off sc0 sc1" ::"v"(p), "v"(v) : "memory");
}
#define VDRAIN()                                      \
  do {                                                \
    asm volatile("s_waitcnt vmcnt(0)" ::: "memory");  \
    __builtin_amdgcn_sched_barrier(0);                \
  } while (0)

// 16 loads covering 8 rows (128 u32/row): A[2r]=row r words[lane], A[2r+1]=words[64+lane]
#define LDH16(A, P)                                             \
  A[0] = g_load_i<0>(P);     A[1] = g_load_i<256>(P);           \
  A[2] = g_load_i<512>(P);   A[3] = g_load_i<768>(P);           \
  A[4] = g_load_i<1024>(P);  A[5] = g_load_i<1280>(P);          \
  A[6] = g_load_i<1536>(P);  A[7] = g_load_i<1792>(P);          \
  A[8] = g_load_i<2048>(P);  A[9] = g_load_i<2304>(P);          \
  A[10] = g_load_i<2560>(P); A[11] = g_load_i<2816>(P);         \
  A[12] = g_load_i<3072>(P); A[13] = g_load_i<3328>(P);         \
  A[14] = g_load_i<3584>(P); A[15] = g_load_i<3840>(P);

#define LDE16(A, P)                                             \
  A[0] = g_load_i<0>(P);    A[1] = g_load_i<32>(P);             \
  A[2] = g_load_i<64>(P);   A[3] = g_load_i<96>(P);             \
  A[4] = g_load_i<128>(P);  A[5] = g_load_i<160>(P);            \
  A[6] = g_load_i<192>(P);  A[7] = g_load_i<224>(P);            \
  A[8] = g_load_i<256>(P);  A[9] = g_load_i<288>(P);            \
  A[10] = g_load_i<320>(P); A[11] = g_load_i<352>(P);           \
  A[12] = g_load_i<384>(P); A[13] = g_load_i<416>(P);           \
  A[14] = g_load_i<448>(P); A[15] = g_load_i<480>(P);

extern "C" __global__ void __launch_bounds__(256, 1)
lstm_persist(const float* __restrict__ x, const float* __restrict__ h0in,
             const float* __restrict__ c0in, const float* __restrict__ wi0,
             const float* __restrict__ hi0, const float* __restrict__ b0,
             const float* __restrict__ wi1, const float* __restrict__ hi1,
             const float* __restrict__ b1, const float* __restrict__ fcw,
             const float* __restrict__ fcb, float* __restrict__ out,
             unsigned* ws_u32) {
  const int bid = blockIdx.x;
  const int grp = bid >> 4, n = bid & 15;
  const int row0 = grp * 32;
  const int hc0 = n * 16;
  const int tid = threadIdx.x;
  const int w = tid >> 6;            // wave = gate type
  const int lane = tid & 63;
  const int lc = lane & 15;
  const int kl = (lane >> 4) * 8;
  const int arow = lane & 15;
  const int ac = tid & 15, ar = tid >> 4;  // activation map
  const int srow = 8 * w;                  // staging rows per wave

  // ws (u32): h0[2][512][128], h1[2][512][128], flag pairs [16][64][2] @262144
  unsigned* h0b = ws_u32;
  unsigned* h1b = ws_u32 + 131072;
  unsigned* flgP = ws_u32 + 262144;
  unsigned* fpw = flgP + grp * 128 + (n * 4 + w) * 2;

  __shared__ unsigned short x_lds[32][136];
  __shared__ unsigned short h0_lds[32][264];
  __shared__ unsigned short h1_lds[32][264];
  __shared__ float gates0[32][72];
  __shared__ float gates1[32][72];

  // ---- persistent weight B-fragments: lane holds W[k=ks*32+kl+j][gcol] ----
  bf16x8 bw0[12];  // [0..3] wi0 (K=128), [4..11] hi0 (K=256)
  bf16x8 bw1[16];  // [0..7] wi1, [8..15] hi1
  const int gcol = w * 256 + hc0 + lc;
  {
#pragma unroll
    for (int ks = 0; ks < 4; ++ks) {
      u16x8 v;
#pragma unroll
      for (int j = 0; j < 8; ++j) v[j] = f2bf(wi0[(ks * 32 + kl + j) * G4 + gcol]);
      bw0[ks] = __builtin_bit_cast(bf16x8, v);
    }
#pragma unroll
    for (int ks = 0; ks < 8; ++ks) {
      u16x8 v;
#pragma unroll
      for (int j = 0; j < 8; ++j) v[j] = f2bf(hi0[(ks * 32 + kl + j) * G4 + gcol]);
      bw0[4 + ks] = __builtin_bit_cast(bf16x8, v);
    }
#pragma unroll
    for (int ks = 0; ks < 8; ++ks) {
      u16x8 v;
#pragma unroll
      for (int j = 0; j < 8; ++j) v[j] = f2bf(wi1[(ks * 32 + kl + j) * G4 + gcol]);
      bw1[ks] = __builtin_bit_cast(bf16x8, v);
    }
#pragma unroll
    for (int ks = 0; ks < 8; ++ks) {
      u16x8 v;
#pragma unroll
      for (int j = 0; j < 8; ++j) v[j] = f2bf(hi1[(ks * 32 + kl + j) * G4 + gcol]);
      bw1[8 + ks] = __builtin_bit_cast(bf16x8, v);
    }
  }

  // biases + c-state in registers (thread owns rows ar, ar+16 at col ac)
  float bb0[4], bb1[4];
#pragma unroll
  for (int q = 0; q < 4; ++q) {
    bb0[q] = b0[q * 256 + hc0 + ac];
    bb1[q] = b1[q * 256 + hc0 + ac];
  }
  float c0r[2], c1r[2];
#pragma unroll
  for (int half = 0; half < 2; ++half) {
    int r = ar + half * 16, rg = row0 + r;
    c0r[half] = c0in[rg * 256 + hc0 + ac];
    c1r[half] = c0in[131072 + rg * 256 + hc0 + ac];
    unsigned short hb0s = f2bf(h0in[rg * 256 + hc0 + ac]);
    unsigned short hb1s = f2bf(h0in[131072 + rg * 256 + hc0 + ac]);
    unsigned o0 = (unsigned)__shfl_down((int)hb0s, 1) & 0xffffu;
    unsigned o1 = (unsigned)__shfl_down((int)hb1s, 1) & 0xffffu;
    if (!(ac & 1)) {
      unsigned ui = 65536u + (unsigned)(rg * 128) + (unsigned)((hc0 + ac) >> 1);
      g_store1(h0b + ui, (unsigned)hb0s | (o0 << 16));
      g_store1(h1b + ui, (unsigned)hb1s | (o1 << 16));
    }
  }
  VDRAIN();  // seeds acked at MALL
  if (lane == 0) g_store2(fpw, 1ull | (2ull << 32));  // flg0=1, flg1=2

  // merged flag-pair poll: lane L watches pair L of this group
  auto waitpair = [&](unsigned need0, unsigned need1) {
    const unsigned* p = flgP + grp * 128 + lane * 2;
    int sp = 0;
    for (;;) {
      unsigned long long v = g_load2(p);
      VDRAIN();
      unsigned f0 = (unsigned)v, f1 = (unsigned)(v >> 32);
      if (__all((int)((f0 >= need0) && (f1 >= need1)))) break;
      if (++sp >= (1 << 17)) break;
    }
  };

  // ---- x prologue: stage x[0], prefetch x[1] ----
  float2 fr[8];
#pragma unroll
  for (int rr = 0; rr < 8; ++rr)
    fr[rr] = *(const float2*)(x + ((size_t)(row0 + srow + rr) << 16) + 2 * lane);
  VDRAIN();
#pragma unroll
  for (int rr = 0; rr < 8; ++rr) {
    unsigned p = (unsigned)f2bf(fr[rr].x) | ((unsigned)f2bf(fr[rr].y) << 16);
    ((unsigned*)&x_lds[srow + rr][0])[lane] = p;
  }
#pragma unroll
  for (int rr = 0; rr < 8; ++rr)
    fr[rr] = *(const float2*)(x + ((size_t)(row0 + srow + rr) << 16) + 128 + 2 * lane);
  __syncthreads();

  f32x4 p10{0.f, 0.f, 0.f, 0.f}, p11{0.f, 0.f, 0.f, 0.f};  // carried wi1*h0 partial

  // iter i: L0 computes step i (i<512); L1 computes step i-2 (i>=2)
  for (int i = 0; i < 514; ++i) {
    // ---- (a) pre-poll: x*wi0 for L0 step i (x_lds holds x[i]) ----
    f32x4 a00{0.f, 0.f, 0.f, 0.f}, a01{0.f, 0.f, 0.f, 0.f};
    if (i < 512) {
#pragma unroll
      for (int ks = 0; ks < 4; ++ks) {
        bf16x8 a0 = *(const bf16x8*)&x_lds[arow][ks * 32 + kl];
        bf16x8 a1 = *(const bf16x8*)&x_lds[16 + arow][ks * 32 + kl];
        a00 = MFMA(a0, bw0[ks], a00);
        a01 = MFMA(a1, bw0[ks], a01);
      }
    }

    // ---- (b) merged poll: h0[i-1] ready (flg0>=i+1) && h1[i-3] ready (flg1>=i) ----
    waitpair((unsigned)(i <= 512 ? i + 1 : 513), (unsigned)i);

    // ---- (c) stage h0[i-1] and h1[i-3] (both parity (i+1)&1) ----
    unsigned ta[16], tb[16];
    if (i <= 512) {
      const unsigned* hp0 = h0b + ((i + 1) & 1) * 65536 + (row0 + srow) * 128 + lane;
      LDH16(ta, hp0);
    }
    if (i >= 2) {
      const unsigned* hp1 = h1b + ((i + 1) & 1) * 65536 + (row0 + srow) * 128 + lane;
      LDH16(tb, hp1);
    }
    VDRAIN();
    if (i <= 512) {
#pragma unroll
      for (int rr = 0; rr < 8; ++rr) {
        unsigned* dst = (unsigned*)&h0_lds[srow + rr][0];
        dst[lane] = ta[2 * rr];
        dst[64 + lane] = ta[2 * rr + 1];
      }
    }
    if (i >= 2) {
#pragma unroll
      for (int rr = 0; rr < 8; ++rr) {
        unsigned* dst = (unsigned*)&h1_lds[srow + rr][0];
        dst[lane] = tb[2 * rr];
        dst[64 + lane] = tb[2 * rr + 1];
      }
    }
    __syncthreads();

    // ---- (d) x[i+1] -> x_lds (barrier-protected single buffer); MFMAs; gates ----
    if (i <= 510) {
#pragma unroll
      for (int rr = 0; rr < 8; ++rr) {
        unsigned p = (unsigned)f2bf(fr[rr].x) | ((unsigned)f2bf(fr[rr].y) << 16);
        ((unsigned*)&x_lds[srow + rr][0])[lane] = p;
      }
    }
    if (i <= 509) {
#pragma unroll
      for (int rr = 0; rr < 8; ++rr)
        fr[rr] = *(const float2*)(x + ((size_t)(row0 + srow + rr) << 16) +
                                  (size_t)(i + 2) * 128 + 2 * lane);
    }
    f32x4 a10 = p10, a11 = p11;  // carried wi1*h0[i-2] partial for L1 step i-2
    if (i < 512) {
#pragma unroll
      for (int ks = 0; ks < 8; ++ks) {  // hi0 * h0[i-1]
        bf16x8 a0 = *(const bf16x8*)&h0_lds[arow][ks * 32 + kl];
        bf16x8 a1 = *(const bf16x8*)&h0_lds[16 + arow][ks * 32 + kl];
        a00 = MFMA(a0, bw0[4 + ks], a00);
        a01 = MFMA(a1, bw0[4 + ks], a01);
      }
    }
    if (i >= 2) {
#pragma unroll
      for (int ks = 0; ks < 8; ++ks) {  // hi1 * h1[i-3]
        bf16x8 a0 = *(const bf16x8*)&h1_lds[arow][ks * 32 + kl];
        bf16x8 a1 = *(const bf16x8*)&h1_lds[16 + arow][ks * 32 + kl];
        a10 = MFMA(a0, bw1[8 + ks], a10);
        a11 = MFMA(a1, bw1[8 + ks], a11);
      }
    }
    if (i >= 1 && i <= 512) {  // wi1 * h0[i-1] -> carry for next iter (L1 step i-1)
      p10 = f32x4{0.f, 0.f, 0.f, 0.f};
      p11 = f32x4{0.f, 0.f, 0.f, 0.f};
#pragma unroll
      for (int ks = 0; ks < 8; ++ks) {
        bf16x8 a0 = *(const bf16x8*)&h0_lds[arow][ks * 32 + kl];
        bf16x8 a1 = *(const bf16x8*)&h0_lds[16 + arow][ks * 32 + kl];
        p10 = MFMA(a0, bw1[ks], p10);
        p11 = MFMA(a1, bw1[ks], p11);
      }
    }
    {
      int col = w * 16 + lc;
      int rbase = (lane >> 4) * 4;  // C/D: row=(lane>>4)*4+j, col=lane&15
      if (i < 512) {
#pragma unroll
        for (int j = 0; j < 4; ++j) {
          gates0[rbase + j][GIDX(rbase + j, col)] = a00[j];
          gates0[16 + rbase + j][GIDX(16 + rbase + j, col)] = a01[j];
        }
      }
      if (i >= 2) {
#pragma unroll
        for (int j = 0; j < 4; ++j) {
          gates1[rbase + j][GIDX(rbase + j, col)] = a10[j];
          gates1[16 + rbase + j][GIDX(16 + rbase + j, col)] = a11[j];
        }
      }
    }
    __syncthreads();

    // ---- (e) activations: L0 step i, L1 step i-2; h stores (parity i&1) ----
    if (i < 512) {
#pragma unroll
      for (int half = 0; half < 2; ++half) {
        int r = ar + half * 16;
        float gi = gates0[r][GIDX(r, ac)] + bb0[0];
        float gf = gates0[r][GIDX(r, 16 + ac)] + bb0[1];
        float gg = gates0[r][GIDX(r, 32 + ac)] + bb0[2];
        float go = gates0[r][GIDX(r, 48 + ac)] + bb0[3];
        float ii = sigm(gi), ff = sigm(gf), g2 = tanh_(gg), oo = sigm(go);
        float c = ff * c0r[half] + ii * g2;
        c0r[half] = c;
        float h = oo * tanh_(c);
        unsigned short hb = f2bf(h);
        unsigned other = (unsigned)__shfl_down((int)hb, 1) & 0xffffu;
        if (!(ac & 1))
          g_store1(h0b + (i & 1) * 65536 + (row0 + r) * 128 + ((hc0 + ac) >> 1),
                   (unsigned)hb | (other << 16));
      }
    }
    if (i >= 2) {
#pragma unroll
      for (int half = 0; half < 2; ++half) {
        int r = ar + half * 16;
        float gi = gates1[r][GIDX(r, ac)] + bb1[0];
        float gf = gates1[r][GIDX(r, 16 + ac)] + bb1[1];
        float gg = gates1[r][GIDX(r, 32 + ac)] + bb1[2];
        float go = gates1[r][GIDX(r, 48 + ac)] + bb1[3];
        float ii = sigm(gi), ff = sigm(gf), g2 = tanh_(gg), oo = sigm(go);
        float c = ff * c1r[half] + ii * g2;
        c1r[half] = c;
        float h = oo * tanh_(c);
        unsigned short hb = f2bf(h);
        unsigned other = (unsigned)__shfl_down((int)hb, 1) & 0xffffu;
        if (!(ac & 1))
          g_store1(h1b + (i & 1) * 65536 + (row0 + r) * 128 + ((hc0 + ac) >> 1),
                   (unsigned)hb | (other << 16));
      }
    }

    // ---- (f) ONE drain, dual-flag post ----
    VDRAIN();
    if (lane == 0) {
      unsigned f0v = (i < 512) ? (unsigned)(i + 2) : 513u;
      unsigned f1v = (i >= 2) ? (unsigned)(i + 1) : 2u;
      g_store2(fpw, (unsigned long long)f0v | ((unsigned long long)f1v << 32));
    }
  }

  // ---- epilogue: out[b] = h1[511][b,:] . fc_w + fc_b (parity 1) ----
  if (n == 0) {
    waitpair(513u, 514u);
    int r = tid >> 3, sg = tid & 7;
    const unsigned* hrow = h1b + 65536 + (row0 + r) * 128 + sg;
    unsigned hv[16];
    LDE16(hv, hrow);
    VDRAIN();
    float sum = 0.f;
#pragma unroll
    for (int q = 0; q < 16; ++q) {
      int k2 = (sg + q * 8) * 2;
      sum += bf2f(hv[q] & 0xffffu) * fcw[k2];
      sum += bf2f(hv[q] >> 16) * fcw[k2 + 1];
    }
    sum += __shfl_down(sum, 4, 8);
    sum += __shfl_down(sum, 2, 8);
    sum += __shfl_down(sum, 1, 8);
    if (sg == 0) out[row0 + r] = sum + fcb[0];
  }
}

extern "C" void kernel_launch(void* const* d_in, const int* in_sizes, int n_in,
                              void* d_out, int out_size, void* d_ws, size_t ws_size,
                              hipStream_t stream) {
  // zero the flag-pair region (byte offset 1 MiB, 8 KiB)
  hipMemsetAsync((char*)d_ws + 1048576, 0, 8192, stream);
  lstm_persist<<<dim3(256), dim3(256), 0, stream>>>(
      (const float*)d_in[0], (const float*)d_in[1], (const float*)d_in[2],
      (const float*)d_in[3], (const float*)d_in[4], (const float*)d_in[5],
      (const float*)d_in[6], (const float*)d_in[7], (const float*)d_in[8],
      (const float*)d_in[9], (const float*)d_in[10], (float*)d_out,
      (unsigned*)d_ws);
}